// Round 2
// baseline (493.964 us; speedup 1.0000x reference)
//
#include <hip/hip_runtime.h>
#include <stdint.h>

// N=16, M=4, D=32, K=256, H=64, W=64
// pixels P = N*M*H*W = 262144
// outputs (concat, all read back as f32): sample (P*256), code (P, WRITE AS FLOAT), logit (P*256)

#define TINY_F 1.17549435082228750797e-38f

// XLA:CPU vectorized log (llvm_ir_runtime GenerateVF32Log, ported from Eigen plog).
// VSL::MulAdd emits UNFUSED mul+add -> replicate with contraction off.
__device__ __forceinline__ float plog_xla(float xin) {
  #pragma clang fp contract(off)
  uint32_t ix = __float_as_uint(xin);
  int e_i = (int)(ix >> 23) - 126;                              // xin = x * 2^e, x in [0.5,1)
  float x = __uint_as_float((ix & 0x007FFFFFu) | 0x3F000000u);
  float e = (float)e_i;
  bool lt = x < 0.707106781186547524f;
  float tmp = lt ? x : 0.0f;
  x = x - 1.0f;                       // exact
  e = e - (lt ? 1.0f : 0.0f);
  x = x + tmp;                        // (x-1)+x = 2x-1, exact
  float z  = x * x;
  float x3 = z * x;
  float y  =  7.0376836292e-2f * x + (-1.1514610310e-1f);
  float y1 = -1.2420140846e-1f * x +   1.4249322787e-1f;
  float y2 =  2.0000714765e-1f * x + (-2.4999993993e-1f);
  y  = y  * x +   1.1676998740e-1f;
  y1 = y1 * x + (-1.6668057665e-1f);
  y2 = y2 * x +   3.3333331174e-1f;
  y  = y * x3 + y1;
  y  = y * x3 + y2;
  y  = y * x3;
  y  = y + e * (-2.12194440e-4f);     // mul then add (unfused)
  x  = x - 0.5f * z;                  // 0.5*z exact -> rounding-identical fused/unfused
  x  = x + y;
  x  = x + e * 0.693359375f;          // e*q2 exact (<=17 mantissa bits)
  return x;
}

__device__ __forceinline__ void threefry2x32(uint32_t k0, uint32_t k1,
                                             uint32_t x0, uint32_t x1,
                                             uint32_t& o0, uint32_t& o1) {
  uint32_t ks2 = k0 ^ k1 ^ 0x1BD11BDAu;
  x0 += k0; x1 += k1;
#define TF_RND(r) { x0 += x1; x1 = (x1 << (r)) | (x1 >> (32 - (r))); x1 ^= x0; }
  TF_RND(13) TF_RND(15) TF_RND(26) TF_RND(6)
  x0 += k1; x1 += ks2 + 1u;
  TF_RND(17) TF_RND(29) TF_RND(16) TF_RND(24)
  x0 += ks2; x1 += k0 + 2u;
  TF_RND(13) TF_RND(15) TF_RND(26) TF_RND(6)
  x0 += k0; x1 += k1 + 3u;
  TF_RND(17) TF_RND(29) TF_RND(16) TF_RND(24)
  x0 += k1; x1 += ks2 + 4u;
  TF_RND(13) TF_RND(15) TF_RND(26) TF_RND(6)
  x0 += ks2; x1 += k0 + 5u;
#undef TF_RND
  o0 = x0; o1 = x1;
}

// JAX uniform(tiny,1): u = (bits>>9 | 1.0bits) - 1; max(tiny, u*(1-tiny)+tiny) == (u>0 ? u : tiny)
__device__ __forceinline__ float gumbel_from_bits(uint32_t bits) {
  uint32_t mant = bits >> 9;
  float f = __uint_as_float(0x3F800000u | mant) - 1.0f;  // exact, [0,1)
  float u = mant ? f : TINY_F;
  float t = -plog_xla(u);
  return -plog_xla(t);
}

constexpr int KK  = 256;
constexpr int DD  = 32;
constexpr int PPB = 16;   // pixels per block (consecutive w)

__global__ __launch_bounds__(256)
void mcq_kernel(const float* __restrict__ x, const float* __restrict__ cb,
                float* __restrict__ sample, float* __restrict__ code,
                float* __restrict__ logit) {
  __shared__ float s_cb[KK * 33];   // +1 pad
  __shared__ float s_x[PPB][DD];
  __shared__ float s_x2[PPB];
  __shared__ float s_bp[4][PPB];
  __shared__ int   s_bi[4][PPB];

  const int t = threadIdx.x;        // k index
  const int pbase = blockIdx.x * PPB;
  const int n  = pbase >> 14;
  const int m  = (pbase >> 12) & 3;
  const int h  = (pbase >> 6) & 63;
  const int w0 = pbase & 63;

  const float* cbm = cb + (size_t)m * (KK * DD);
  for (int i = t; i < KK * DD; i += 256)
    s_cb[(i >> 5) * 33 + (i & 31)] = cbm[i];

  const float* xb = x + ((size_t)(n * 128 + m * 32)) * 4096 + h * 64 + w0;
  for (int j = t; j < PPB * DD; j += 256) {
    int d = j >> 4, wi = j & 15;
    s_x[wi][d] = xb[(size_t)d * 4096 + wi];
  }
  __syncthreads();

  // c row (k = t) in regs; c2 = UNFUSED ascending chain (XLA reduce of cb*cb)
  float c[DD];
  #pragma unroll
  for (int d = 0; d < DD; d++) c[d] = s_cb[t * 33 + d];
  float c2;
  {
    #pragma clang fp contract(off)
    c2 = 0.0f;
    #pragma unroll
    for (int d = 0; d < DD; d++) c2 = c2 + c[d] * c[d];
  }
  // x2 once per pixel (threads 0..15), UNFUSED ascending chain
  if (t < PPB) {
    #pragma clang fp contract(off)
    float a = 0.0f;
    #pragma unroll
    for (int d = 0; d < DD; d++) a = a + s_x[t][d] * s_x[t][d];
    s_x2[t] = a;
  }
  __syncthreads();

  const int lane = t & 63, wv = t >> 6;

  for (int pi = 0; pi < PPB; pi++) {
    const int gp = pbase + pi;

    // inter: FUSED ascending fma chain (Eigen gebp path)
    float inter = 0.0f;
    #pragma unroll
    for (int d = 0; d < DD; d++)
      inter = __builtin_fmaf(s_x[pi][d], c[d], inter);

    float dist = (s_x2[pi] + c2) - 2.0f * inter;   // 2*inter exact
    float L = plog_xla(dist);
    logit[(size_t)gp * KK + t] = L;

    // partitionable threefry: counter=(0, linear idx), bits = v0^v1
    uint32_t l = (uint32_t)gp * 256u + (uint32_t)t;
    uint32_t v0, v1;
    threefry2x32(0u, 42u, 0u, l, v0, v1);
    float g = gumbel_from_bits(v0 ^ v1);
    float phi = g + L;

    // wave argmax, strict > with ties -> smaller index (jnp.argmax first-occurrence)
    float bphi = phi; int bidx = t;
    #pragma unroll
    for (int off = 32; off >= 1; off >>= 1) {
      float op = __shfl_xor(bphi, off, 64);
      int   oi = __shfl_xor(bidx, off, 64);
      if (op > bphi || (op == bphi && oi < bidx)) { bphi = op; bidx = oi; }
    }
    if (lane == 0) { s_bp[wv][pi] = bphi; s_bi[wv][pi] = bidx; }
  }
  __syncthreads();

  // epilogue: every thread redundantly finalizes per-pixel block winner (no more syncs)
  for (int pi = 0; pi < PPB; pi++) {
    float bb = s_bp[0][pi]; int bi = s_bi[0][pi];
    #pragma unroll
    for (int wv2 = 1; wv2 < 4; wv2++) {
      float op = s_bp[wv2][pi]; int oi = s_bi[wv2][pi];
      if (op > bb || (op == bb && oi < bi)) { bb = op; bi = oi; }
    }
    const int gp = pbase + pi;
    sample[(size_t)gp * KK + t] = (t == bi) ? 1.0f : 0.0f;
    if (t == pi) code[gp] = (float)bi;   // code output is read back as f32 -> write float!
  }
}

extern "C" void kernel_launch(void* const* d_in, const int* in_sizes, int n_in,
                              void* d_out, int out_size, void* d_ws, size_t ws_size,
                              hipStream_t stream) {
  const float* x  = (const float*)d_in[0];
  const float* cb = (const float*)d_in[1];

  float* out_f  = (float*)d_out;
  float* sample = out_f;                       // 67108864
  float* code   = out_f + 67108864;            // 262144 (as float)
  float* logit  = out_f + 67108864 + 262144;   // 67108864

  mcq_kernel<<<262144 / PPB, 256, 0, stream>>>(x, cb, sample, code, logit);
}

// Round 3
// 474.769 us; speedup vs baseline: 1.0404x; 1.0404x over previous
//
#include <hip/hip_runtime.h>
#include <stdint.h>

// N=16, M=4, D=32, K=256, H=64, W=64
// pixels P = N*M*H*W = 262144
// outputs (concat, read back as f32): sample (P*256), code (P, written as float), logit (P*256)

#define TINY_F 1.17549435082228750797e-38f

// XLA:CPU vectorized log (GenerateVF32Log / Eigen plog), UNFUSED mul+add.
// Bit-exactness verified round 2 (code absmax == 0). DO NOT TOUCH.
__device__ __forceinline__ float plog_xla(float xin) {
  #pragma clang fp contract(off)
  uint32_t ix = __float_as_uint(xin);
  int e_i = (int)(ix >> 23) - 126;
  float x = __uint_as_float((ix & 0x007FFFFFu) | 0x3F000000u);
  float e = (float)e_i;
  bool lt = x < 0.707106781186547524f;
  float tmp = lt ? x : 0.0f;
  x = x - 1.0f;
  e = e - (lt ? 1.0f : 0.0f);
  x = x + tmp;
  float z  = x * x;
  float x3 = z * x;
  float y  =  7.0376836292e-2f * x + (-1.1514610310e-1f);
  float y1 = -1.2420140846e-1f * x +   1.4249322787e-1f;
  float y2 =  2.0000714765e-1f * x + (-2.4999993993e-1f);
  y  = y  * x +   1.1676998740e-1f;
  y1 = y1 * x + (-1.6668057665e-1f);
  y2 = y2 * x +   3.3333331174e-1f;
  y  = y * x3 + y1;
  y  = y * x3 + y2;
  y  = y * x3;
  y  = y + e * (-2.12194440e-4f);
  x  = x - 0.5f * z;
  x  = x + y;
  x  = x + e * 0.693359375f;
  return x;
}

__device__ __forceinline__ void threefry2x32(uint32_t k0, uint32_t k1,
                                             uint32_t x0, uint32_t x1,
                                             uint32_t& o0, uint32_t& o1) {
  uint32_t ks2 = k0 ^ k1 ^ 0x1BD11BDAu;
  x0 += k0; x1 += k1;
#define TF_RND(r) { x0 += x1; x1 = (x1 << (r)) | (x1 >> (32 - (r))); x1 ^= x0; }
  TF_RND(13) TF_RND(15) TF_RND(26) TF_RND(6)
  x0 += k1; x1 += ks2 + 1u;
  TF_RND(17) TF_RND(29) TF_RND(16) TF_RND(24)
  x0 += ks2; x1 += k0 + 2u;
  TF_RND(13) TF_RND(15) TF_RND(26) TF_RND(6)
  x0 += k0; x1 += k1 + 3u;
  TF_RND(17) TF_RND(29) TF_RND(16) TF_RND(24)
  x0 += k1; x1 += ks2 + 4u;
  TF_RND(13) TF_RND(15) TF_RND(26) TF_RND(6)
  x0 += ks2; x1 += k0 + 5u;
#undef TF_RND
  o0 = x0; o1 = x1;
}

__device__ __forceinline__ float gumbel_from_bits(uint32_t bits) {
  uint32_t mant = bits >> 9;
  float f = __uint_as_float(0x3F800000u | mant) - 1.0f;
  float u = mant ? f : TINY_F;
  float t = -plog_xla(u);
  return -plog_xla(t);
}

constexpr int KK  = 256;
constexpr int DD  = 32;
constexpr int PPB = 16;

__global__ __launch_bounds__(256, 4)
void mcq_kernel(const float* __restrict__ x, const float* __restrict__ cb,
                float* __restrict__ sample, float* __restrict__ code,
                float* __restrict__ logit) {
  __shared__ float s_cb[KK * 33];     // +1 pad: (t+d)%32 banks, conflict-free b32
  __shared__ float s_x[PPB][DD];      // 128B rows, 16B aligned for b128 broadcast
  __shared__ float s_x2[PPB];
  __shared__ float s_bp[4][PPB];
  __shared__ int   s_bi[4][PPB];

  const int t = threadIdx.x;          // k index
  const int pbase = blockIdx.x * PPB;
  const int n  = pbase >> 14;
  const int m  = (pbase >> 12) & 3;
  const int h  = (pbase >> 6) & 63;
  const int w0 = pbase & 63;

  const float* cbm = cb + (size_t)m * (KK * DD);
  for (int i = t; i < KK * DD; i += 256)
    s_cb[(i >> 5) * 33 + (i & 31)] = cbm[i];

  const float* xb = x + ((size_t)(n * 128 + m * 32)) * 4096 + h * 64 + w0;
  for (int j = t; j < PPB * DD; j += 256) {
    int d = j >> 4, wi = j & 15;
    s_x[wi][d] = xb[(size_t)d * 4096 + wi];
  }
  __syncthreads();

  // codebook row k=t -> REGISTERS (read once; conflict-free via pad-33)
  float c[DD];
  #pragma unroll
  for (int d = 0; d < DD; d++) c[d] = s_cb[t * 33 + d];
  float c2;
  {
    #pragma clang fp contract(off)
    c2 = 0.0f;
    #pragma unroll
    for (int d = 0; d < DD; d++) c2 = c2 + c[d] * c[d];
  }
  if (t < PPB) {
    #pragma clang fp contract(off)
    float a = 0.0f;
    #pragma unroll
    for (int d = 0; d < DD; d++) a = a + s_x[t][d] * s_x[t][d];
    s_x2[t] = a;
  }
  __syncthreads();

  const int lane = t & 63, wv = t >> 6;
  float* Lp = logit + (size_t)pbase * KK + t;

  for (int pi = 0; pi < PPB; pi += 2) {
    const int gpA = pbase + pi, gpB = gpA + 1;

    // x rows via b128 broadcast reads
    const float4* xpA = (const float4*)s_x[pi];
    const float4* xpB = (const float4*)s_x[pi + 1];
    float interA = 0.0f, interB = 0.0f;
    #pragma unroll
    for (int j = 0; j < 8; j++) {
      float4 qa = xpA[j];
      float4 qb = xpB[j];
      interA = __builtin_fmaf(qa.x, c[4*j+0], interA);
      interB = __builtin_fmaf(qb.x, c[4*j+0], interB);
      interA = __builtin_fmaf(qa.y, c[4*j+1], interA);
      interB = __builtin_fmaf(qb.y, c[4*j+1], interB);
      interA = __builtin_fmaf(qa.z, c[4*j+2], interA);
      interB = __builtin_fmaf(qb.z, c[4*j+2], interB);
      interA = __builtin_fmaf(qa.w, c[4*j+3], interA);
      interB = __builtin_fmaf(qb.w, c[4*j+3], interB);
    }

    float distA = (s_x2[pi]     + c2) - 2.0f * interA;
    float distB = (s_x2[pi + 1] + c2) - 2.0f * interB;
    float LA = plog_xla(distA);
    float LB = plog_xla(distB);
    Lp[(size_t)pi * KK]       = LA;
    Lp[(size_t)(pi + 1) * KK] = LB;

    uint32_t lA = (uint32_t)gpA * 256u + (uint32_t)t;
    uint32_t lB = lA + 256u;
    uint32_t a0, a1, b0, b1;
    threefry2x32(0u, 42u, 0u, lA, a0, a1);
    threefry2x32(0u, 42u, 0u, lB, b0, b1);
    float gA = gumbel_from_bits(a0 ^ a1);
    float gB = gumbel_from_bits(b0 ^ b1);
    float phiA = gA + LA;
    float phiB = gB + LB;

    // wave argmax (strict >, ties -> smaller index), two pixels interleaved
    float bpA = phiA, bpB = phiB;
    int   biA = t,    biB = t;
    #pragma unroll
    for (int off = 32; off >= 1; off >>= 1) {
      float opA = __shfl_xor(bpA, off, 64);
      int   oiA = __shfl_xor(biA, off, 64);
      float opB = __shfl_xor(bpB, off, 64);
      int   oiB = __shfl_xor(biB, off, 64);
      if (opA > bpA || (opA == bpA && oiA < biA)) { bpA = opA; biA = oiA; }
      if (opB > bpB || (opB == bpB && oiB < biB)) { bpB = opB; biB = oiB; }
    }
    if (lane == 0) {
      s_bp[wv][pi] = bpA;     s_bi[wv][pi] = biA;
      s_bp[wv][pi + 1] = bpB; s_bi[wv][pi + 1] = biB;
    }
  }
  __syncthreads();

  // epilogue: every thread finalizes block winners (no further syncs)
  for (int pi = 0; pi < PPB; pi++) {
    float bb = s_bp[0][pi]; int bi = s_bi[0][pi];
    #pragma unroll
    for (int wv2 = 1; wv2 < 4; wv2++) {
      float op = s_bp[wv2][pi]; int oi = s_bi[wv2][pi];
      if (op > bb || (op == bb && oi < bi)) { bb = op; bi = oi; }
    }
    const int gp = pbase + pi;
    sample[(size_t)gp * KK + t] = (t == bi) ? 1.0f : 0.0f;
    if (t == pi) code[gp] = (float)bi;
  }
}

extern "C" void kernel_launch(void* const* d_in, const int* in_sizes, int n_in,
                              void* d_out, int out_size, void* d_ws, size_t ws_size,
                              hipStream_t stream) {
  const float* x  = (const float*)d_in[0];
  const float* cb = (const float*)d_in[1];

  float* out_f  = (float*)d_out;
  float* sample = out_f;                       // 67108864
  float* code   = out_f + 67108864;            // 262144 (as float)
  float* logit  = out_f + 67108864 + 262144;   // 67108864

  mcq_kernel<<<262144 / PPB, 256, 0, stream>>>(x, cb, sample, code, logit);
}